// Round 1
// baseline (211.066 us; speedup 1.0000x reference)
//
#include <hip/hip_runtime.h>

#define NH   32
#define NHK  8
#define D    128
#define QB   128
#define KB   64

typedef float f32x16 __attribute__((ext_vector_type(16)));
typedef short bf16x8 __attribute__((ext_vector_type(8)));
typedef short short4v __attribute__((ext_vector_type(4)));

__device__ __forceinline__ unsigned short f2bf(float x) {
  unsigned u = __builtin_bit_cast(unsigned, x);
  u += 0x7fffu + ((u >> 16) & 1u);
  return (unsigned short)(u >> 16);
}

__global__ __launch_bounds__(256, 2)
void swa_fwd(const float* __restrict__ qg, const float* __restrict__ kg,
             const float* __restrict__ vg, float* __restrict__ og)
{
  __shared__ __align__(16) short lds_k[KB * D];      // [j][d], XOR-swizzled rows
  __shared__ __align__(16) short lds_v[D * KB];      // [d][j] (V^T), XOR-swizzled
  __shared__ __align__(16) short lds_p[4 * 32 * KB]; // per-wave P^T as [i][j]

  const int tid  = threadIdx.x;
  const int lane = tid & 63;
  const int w    = tid >> 6;
  const int il   = lane & 31;
  const int half = lane >> 5;

  // XCD-aware swizzle: xcd (= blockIdx%8) <- one kv-head; within: g fast, then qb
  int b    = blockIdx.x;
  int lidx = (b & 7) * 256 + (b >> 3);
  int hk   = lidx >> 8;
  int rem  = lidx & 255;
  int bq   = rem >> 2;
  int h    = hk * 4 + (rem & 3);
  int qs   = bq * QB;

  const float qscale = 0.088388347648318447f * 1.4426950408889634f; // 1/sqrt(128)*log2(e)

  // ---- Q fragments (B-operand layout for swapped QK^T), hoisted ----
  bf16x8 qf[8];
  {
    const float* qp = qg + ((size_t)(qs + 32*w + il) * NH + h) * D + half * 8;
    #pragma unroll
    for (int ks = 0; ks < 8; ++ks) {
      float4 a = *(const float4*)(qp + ks*16);
      float4 c = *(const float4*)(qp + ks*16 + 4);
      bf16x8 f;
      f[0] = (short)f2bf(a.x * qscale); f[1] = (short)f2bf(a.y * qscale);
      f[2] = (short)f2bf(a.z * qscale); f[3] = (short)f2bf(a.w * qscale);
      f[4] = (short)f2bf(c.x * qscale); f[5] = (short)f2bf(c.y * qscale);
      f[6] = (short)f2bf(c.z * qscale); f[7] = (short)f2bf(c.w * qscale);
      qf[ks] = f;
    }
  }

  f32x16 acc_o[4];
  #pragma unroll
  for (int dt = 0; dt < 4; ++dt)
    #pragma unroll
    for (int r = 0; r < 16; ++r) acc_o[dt][r] = 0.0f;

  float m_run = -64.0f;   // floor: masked exp2(-1e30 - m) == 0, never the p=1 trap
  float l_run = 0.0f;

  int t_lo = 2*bq - 8; if (t_lo < 0) t_lo = 0;
  int t_hi = 2*bq + 1;
  const int iw_min = qs + 32*w;

  for (int t = t_lo; t <= t_hi; ++t) {
    const int kt = t * KB;

    // ---- stage K: row-major bf16, swizzle elem ^= (row&7)<<3 ----
    {
      int j  = tid >> 2;
      int dq = (tid & 3) * 32;
      const float* kp = kg + ((size_t)(kt + j) * NHK + hk) * D + dq;
      float tmp[32];
      #pragma unroll
      for (int c = 0; c < 8; ++c) {
        float4 x = *(const float4*)(kp + c*4);
        tmp[c*4+0]=x.x; tmp[c*4+1]=x.y; tmp[c*4+2]=x.z; tmp[c*4+3]=x.w;
      }
      int base = j * D + dq;
      int swz  = (j & 7) << 3;
      #pragma unroll
      for (int c = 0; c < 4; ++c) {
        bf16x8 s;
        #pragma unroll
        for (int e = 0; e < 8; ++e) s[e] = (short)f2bf(tmp[c*8+e]);
        *(bf16x8*)&lds_k[(base + c*8) ^ swz] = s;
      }
    }
    // ---- stage V transposed: Vt[d][j], swizzle elem ^= (d&7)<<3 ----
    {
      int d0 = (tid & 31) * 4;
      int j0 = (tid >> 5) * 8;
      float tv[8][4];
      #pragma unroll
      for (int r = 0; r < 8; ++r) {
        float4 x = *(const float4*)(vg + ((size_t)(kt + j0 + r) * NHK + hk) * D + d0);
        tv[r][0]=x.x; tv[r][1]=x.y; tv[r][2]=x.z; tv[r][3]=x.w;
      }
      #pragma unroll
      for (int c = 0; c < 4; ++c) {
        int d = d0 + c;
        bf16x8 s;
        #pragma unroll
        for (int r = 0; r < 8; ++r) s[r] = (short)f2bf(tv[r][c]);
        *(bf16x8*)&lds_v[(d * KB + j0) ^ ((d & 7) << 3)] = s;
      }
    }
    __syncthreads();

    // ---- compute (wave-uniform skip; barriers stay outside) ----
    bool skip = (kt > iw_min + 31) || (kt + KB - 1 < iw_min - 511);
    if (!skip) {
      // QK^T swapped: S^T[j][i] = sum_d K[j][d] * Q[i][d]
      f32x16 acc_s[2];
      #pragma unroll
      for (int mt = 0; mt < 2; ++mt)
        #pragma unroll
        for (int r = 0; r < 16; ++r) acc_s[mt][r] = 0.0f;

      #pragma unroll
      for (int ks = 0; ks < 8; ++ks) {
        #pragma unroll
        for (int mt = 0; mt < 2; ++mt) {
          int jrow = mt*32 + il;
          bf16x8 a = *(const bf16x8*)&lds_k[(jrow * D + ks*16 + half*8) ^ ((jrow & 7) << 3)];
          acc_s[mt] = __builtin_amdgcn_mfma_f32_32x32x16_bf16(a, qf[ks], acc_s[mt], 0, 0, 0);
        }
      }

      // masking (edge tiles only)
      bool do_causal = (kt + KB - 1 > iw_min);
      bool do_window = (kt < iw_min + 31 - 511);
      if (do_causal || do_window) {
        int base0 = kt - iw_min - il + 4*half;
        #pragma unroll
        for (int mt = 0; mt < 2; ++mt)
          #pragma unroll
          for (int r = 0; r < 16; ++r) {
            int delta = base0 + 32*mt + (r & 3) + 8*(r >> 2); // j - i
            if ((do_causal && delta > 0) || (do_window && delta < -511))
              acc_s[mt][r] = -1e30f;
          }
      }

      // online softmax (per q-column i = lane&31; reduce over 32 regs + xor-32)
      float tm = acc_s[0][0];
      #pragma unroll
      for (int mt = 0; mt < 2; ++mt)
        #pragma unroll
        for (int r = 0; r < 16; ++r) tm = fmaxf(tm, acc_s[mt][r]);
      tm = fmaxf(tm, __shfl_xor(tm, 32));
      float m_new  = fmaxf(m_run, tm);
      float fscale = __builtin_amdgcn_exp2f(m_run - m_new);
      m_run = m_new;

      float psum = 0.0f;
      #pragma unroll
      for (int mt = 0; mt < 2; ++mt)
        #pragma unroll
        for (int r = 0; r < 16; ++r) {
          float p = __builtin_amdgcn_exp2f(acc_s[mt][r] - m_new);
          acc_s[mt][r] = p;
          psum += p;
        }
      psum += __shfl_xor(psum, 32);
      l_run = l_run * fscale + psum;
      #pragma unroll
      for (int dt = 0; dt < 4; ++dt)
        #pragma unroll
        for (int r = 0; r < 16; ++r) acc_o[dt][r] *= fscale;

      // P^T -> per-wave LDS [i][j] (b64 writes of 4 consecutive j)
      const int pbase = w * (32*KB) + il * KB;
      const int swzp  = (il & 7) << 3;
      #pragma unroll
      for (int mt = 0; mt < 2; ++mt)
        #pragma unroll
        for (int rg = 0; rg < 4; ++rg) {
          short4v s4;
          #pragma unroll
          for (int e = 0; e < 4; ++e) s4[e] = (short)f2bf(acc_s[mt][rg*4 + e]);
          int j0 = 32*mt + 8*rg + 4*half;
          *(short4v*)&lds_p[(pbase + j0) ^ swzp] = s4;
        }

      // PV: O^T[d][i] += V^T[d][j] * P^T[j][i]
      #pragma unroll
      for (int ks = 0; ks < 4; ++ks) {
        bf16x8 pb = *(const bf16x8*)&lds_p[(pbase + ks*16 + half*8) ^ swzp];
        #pragma unroll
        for (int dt = 0; dt < 4; ++dt) {
          int d = dt*32 + il;
          bf16x8 a = *(const bf16x8*)&lds_v[(d * KB + ks*16 + half*8) ^ ((d & 7) << 3)];
          acc_o[dt] = __builtin_amdgcn_mfma_f32_32x32x16_bf16(a, pb, acc_o[dt], 0, 0, 0);
        }
      }
    }
    __syncthreads();
  }

  // ---- epilogue: O = acc / l ----
  float inv_l = 1.0f / l_run;
  const size_t orow = ((size_t)(qs + 32*w + il) * NH + h) * D;
  #pragma unroll
  for (int dt = 0; dt < 4; ++dt)
    #pragma unroll
    for (int rg = 0; rg < 4; ++rg) {
      float4 o;
      o.x = acc_o[dt][rg*4+0] * inv_l;
      o.y = acc_o[dt][rg*4+1] * inv_l;
      o.z = acc_o[dt][rg*4+2] * inv_l;
      o.w = acc_o[dt][rg*4+3] * inv_l;
      *(float4*)(og + orow + dt*32 + 8*rg + 4*half) = o;
    }
}

extern "C" void kernel_launch(void* const* d_in, const int* in_sizes, int n_in,
                              void* d_out, int out_size, void* d_ws, size_t ws_size,
                              hipStream_t stream) {
  const float* q = (const float*)d_in[0];
  const float* k = (const float*)d_in[1];
  const float* v = (const float*)d_in[2];
  float* o = (float*)d_out;
  dim3 grid(2048), block(256);
  hipLaunchKernelGGL(swa_fwd, grid, block, 0, stream, q, k, v, o);
}